// Round 1
// 1153.408 us; speedup vs baseline: 1.0784x; 1.0784x over previous
//
#include <hip/hip_runtime.h>
#include <hip/hip_bf16.h>

// Fenwick TreeLSTM, N=32768, D=256 — fused GEMM+cell.
// Round-2 changes vs round-1 (1240 µs baseline):
//  (1) K-loop: double-buffered LDS, ONE raw s_barrier + vmcnt(0) per K-step;
//      stage(kk+1) issues before ds_read+MFMA of kk so global latency hides
//      under compute (old: __syncthreads drained vmcnt with nothing in flight).
//  (2) phase-2 GEMM processes only non-first-touch rows (packed mapping
//      i = r + r/(2^k-1) + 1); first-touch (node-copy) rows handled by one
//      upfront seed_even kernel (absorbs copy_k15, kills k=14 merge).
//  (3) out h-half written only at k == MSB(t) (intermediate h never read);
//      sth written only if a future iteration reads it.
//  (4) XCD-aware bijective block swizzle: 8 bn-blocks of one bm → same XCD L2.

typedef unsigned short u16;
typedef unsigned int u32;
using short8  = __attribute__((ext_vector_type(8))) short;
using float4v = __attribute__((ext_vector_type(4))) float;

// ---- workspace layout (bytes) ----
// WmT  @ 0         : 1280x512 bf16 gate-permuted (1,310,720)
// WsT  @ 1310720   : 1280x512 bf16 gate-permuted (1,310,720)
// h0b  @ 2621440   : 32768x256 bf16 (16,777,216)
// hlv  @ 19398656  : levels 1..15 h bf16 (16,777,216)
// clv  @ 36175872  : levels 1..15 c fp32 (33,554,432)
// sth  @ 69730304  : state_h bf16, stable copy (16,777,216)
// sthN @ 86507520  : state_h bf16, iteration-k writes (16,777,216)
// total ~103.3 MB

__device__ __forceinline__ u16 f2bf(float f) {
  u32 u = __float_as_uint(f);
  u = (u + 0x7FFFu + ((u >> 16) & 1u)) >> 16;
  return (u16)u;
}
__device__ __forceinline__ float bf2f(u16 h) {
  return __uint_as_float(((u32)h) << 16);
}
__device__ __forceinline__ float sigf(float x) { return 1.0f / (1.0f + __expf(-x)); }
__device__ __forceinline__ float tanhfast(float x) {
  return 2.0f / (1.0f + __expf(-2.0f * x)) - 1.0f;
}

__device__ __forceinline__ void async16(const void* g, void* l) {
  __builtin_amdgcn_global_load_lds((const __attribute__((address_space(1))) void*)g,
                                   (__attribute__((address_space(3))) void*)l,
                                   16, 0, 0);
}

// A-row gather: row i of A = concat(hl(256 bf16), hr(256 bf16)).
// mode 1 takes PACKED row r (non-first-touch only): i = r + r/(2^k-1) + 1.
__device__ __forceinline__ void row_srcs(int mode, int k, int row,
                                         const u16* h0b, const u16* hlv, const u16* sth,
                                         const u16*& pL, const u16*& pR) {
  if (mode == 0) {
    const u16* pb = (k == 1) ? h0b : (hlv + (size_t)(32768 - (1 << (17 - k))) * 256);
    pL = pb + (size_t)(2 * row) * 256;
    pR = pb + (size_t)(2 * row + 1) * 256;
  } else {
    const int Dk = (1 << k) - 1;
    const int i = row + row / Dk + 1;
    const int t = ((i >> k) << (k + 1)) | (1 << k) | (i & Dk);
    pL = sth + (size_t)(t - 1) * 256;
    const int idx = (t >> (k + 1)) * 2;
    pR = hlv + (size_t)((32768 - (1 << (16 - k))) + idx) * 256;
  }
}

// Fused GEMM + LSTM cell.
// Block tile: 128 rows x 160 cols (5 gates x 32 d), BK=32, 16 K-steps.
// 4 waves as 2(m) x 2(n): wave = 64 rows x 16 d's, acc[4 m-tiles][5 gates].
// LDS double buffer: [A 4096 u16 | B 5120 u16] x 2 = 36864 B.
__global__ __launch_bounds__(256) void gemm_cell(
    int mode, int k, int Mc,
    const u16* WT, const float* bias,
    const u16* h0b, const u16* hlv, const u16* sth_in,
    const float* cpar, float* cout, u16* hout,
    const float* clv, float* out, u16* sth_out)
{
  __shared__ __align__(16) u16 smem[18432];
  const int tid  = threadIdx.x;
  const int lane = tid & 63;
  const int w    = tid >> 6;
  const int wm   = w >> 1, wn = w & 1;

  // XCD swizzle: bid%8 = XCD (typical round-robin); give each XCD a
  // contiguous id range so the 8 bn-blocks of one bm share an L2.
  // Bijective since gridDim.x is always a multiple of 8.
  const int nwg = gridDim.x;
  const int q8  = nwg >> 3;
  const int id  = (blockIdx.x & 7) * q8 + (blockIdx.x >> 3);
  const int bm  = id >> 3, bn = id & 7;

  // ---- A staging: 512 slots (row = f>>2, 16B seg = f&3), 2 rounds ----
  const int f0 = w * 128 + lane;
  const int f1 = f0 + 64;
  int rl0 = bm * 128 + (f0 >> 2); if (rl0 > Mc - 1) rl0 = Mc - 1;
  int rl1 = bm * 128 + (f1 >> 2); if (rl1 > Mc - 1) rl1 = Mc - 1;
  const u16 *p0L, *p0R, *p1L, *p1R;
  row_srcs(mode, k, rl0, h0b, hlv, sth_in, p0L, p0R);
  row_srcs(mode, k, rl1, h0b, hlv, sth_in, p1L, p1R);
  const int sa0 = (f0 & 3) * 8, sa1 = (f1 & 3) * 8;
  u16* ldsA0 = smem + (w * 2 + 0) * 512;
  u16* ldsA1 = smem + (w * 2 + 1) * 512;

  // ---- B staging: 640 slots over 10 chunks of 16 rows; 3 rounds ----
  const int ch0 = 0 * 4 + w, ch1 = 1 * 4 + w, ch2 = 2 * 4 + w;  // ch2 valid for w<2
  const u16* pB0 = WT + (size_t)(bn * 160 + ch0 * 16 + (lane >> 2)) * 512 + (lane & 3) * 8;
  const u16* pB1 = WT + (size_t)(bn * 160 + ch1 * 16 + (lane >> 2)) * 512 + (lane & 3) * 8;
  const u16* pB2 = (ch2 < 10)
      ? WT + (size_t)(bn * 160 + ch2 * 16 + (lane >> 2)) * 512 + (lane & 3) * 8
      : pB0;
  u16* ldsB0 = smem + 4096 + ch0 * 512;
  u16* ldsB1 = smem + 4096 + ch1 * 512;
  u16* ldsB2 = smem + 4096 + (ch2 < 10 ? ch2 : 0) * 512;

  float4v acc[4][5];
#pragma unroll
  for (int i = 0; i < 4; ++i)
#pragma unroll
    for (int j = 0; j < 5; ++j) acc[i][j] = (float4v){0.f, 0.f, 0.f, 0.f};

  const int mrow = lane & 15;
  const int kg   = lane >> 4;
  const u16* aBase = smem + (wm * 64 + mrow) * 32 + kg * 8;
  const u16* bBase = smem + 4096 + (wn * 16 + mrow) * 32 + kg * 8;  // + g*1024

  auto stage = [&](int bo, int kk) {
    const u16* s0 = (kk < 8) ? (p0L + sa0 + kk * 32) : (p0R + sa0 + (kk - 8) * 32);
    const u16* s1 = (kk < 8) ? (p1L + sa1 + kk * 32) : (p1R + sa1 + (kk - 8) * 32);
    async16(s0, ldsA0 + bo);
    async16(s1, ldsA1 + bo);
    async16(pB0 + kk * 32, ldsB0 + bo);
    async16(pB1 + kk * 32, ldsB1 + bo);
    if (ch2 < 10) async16(pB2 + kk * 32, ldsB2 + bo);
  };

  // prologue: stage K-step 0 into buf0, drain, barrier
  stage(0, 0);
  asm volatile("s_waitcnt vmcnt(0)" ::: "memory");
  __builtin_amdgcn_s_barrier();

  // 2-phase pipeline: one vmcnt(0)+barrier per K-step; stage(kk+1) hides
  // under ds_read+MFMA of kk. buf[p] holds K-step p&1.
#pragma unroll 2
  for (int kk = 0; kk < 16; ++kk) {
    const int cu = (kk & 1) * 9216;
    if (kk < 15) stage(9216 - cu, kk + 1);
    short8 af[4], bfv[5];
    const u16* aB = aBase + cu;
    const u16* bB = bBase + cu;
#pragma unroll
    for (int mt = 0; mt < 4; ++mt) af[mt]  = *(const short8*)(aB + mt * 512);
#pragma unroll
    for (int g = 0; g < 5; ++g)   bfv[g]  = *(const short8*)(bB + g * 1024);
#pragma unroll
    for (int mt = 0; mt < 4; ++mt)
#pragma unroll
      for (int g = 0; g < 5; ++g)
        acc[mt][g] = __builtin_amdgcn_mfma_f32_16x16x32_bf16(af[mt], bfv[g], acc[mt][g], 0, 0, 0);
    asm volatile("s_waitcnt vmcnt(0)" ::: "memory");
    __builtin_amdgcn_s_barrier();
  }

  // ---- fused cell epilogue ----
  // lane owns d = bn*32 + wn*16 + mrow; rows r0..r0+3 per m-tile.
  const int d = bn * 32 + wn * 16 + mrow;
  const float bi  = bias[d];
  const float bo_ = bias[256 + d];
  const float bu  = bias[512 + d];
  const float bfl = bias[768 + d];
  const float bfr2= bias[1024 + d];

#pragma unroll
  for (int mt = 0; mt < 4; ++mt) {
    const int r0 = bm * 128 + wm * 64 + mt * 16 + kg * 4;
#pragma unroll
    for (int r = 0; r < 4; ++r) {
      const int row = r0 + r;
      if (row >= Mc) continue;
      const float zi  = acc[mt][0][r] + bi;
      const float zo  = acc[mt][1][r] + bo_;
      const float zu  = acc[mt][2][r] + bu;
      const float zfl = acc[mt][3][r] + bfl;
      const float zfr = acc[mt][4][r] + bfr2;
      if (mode == 0) {
        const float cl = cpar[(size_t)(2 * row) * 256 + d];
        const float cr = cpar[(size_t)(2 * row + 1) * 256 + d];
        const float c = sigf(zi) * tanhfast(zu) + sigf(zfl) * cl + sigf(zfr) * cr;
        const float h = sigf(zo) * tanhfast(c);
        cout[(size_t)row * 256 + d] = c;
        hout[(size_t)row * 256 + d] = f2bf(h);
      } else {
        // packed row -> logical i; all rows are non-first-touch here
        const int Dk  = (1 << k) - 1;
        const int i   = row + row / Dk + 1;
        const int t   = ((i >> k) << (k + 1)) | (1 << k) | (i & Dk);
        const int lk  = 32768 - (1 << (16 - k));
        const int idx = (t >> (k + 1)) * 2;
        const float cr = clv[(size_t)(lk + idx) * 256 + d];
        const float cl = out[(size_t)(t - 1) * 512 + 256 + d];
        const float c = sigf(zi) * tanhfast(zu) + sigf(zfl) * cl + sigf(zfr) * cr;
        const float h = sigf(zo) * tanhfast(c);
        out[(size_t)(t - 1) * 512 + 256 + d] = c;
        if ((i >> k) == 0) {
          out[(size_t)(t - 1) * 512 + d] = h;          // k == MSB(t): final h
        } else {
          sth_out[(size_t)(t - 1) * 256 + d] = f2bf(h); // future iterations read
        }
      }
    }
  }
}

// merge iteration-k state rows: sth[t-1] <- sthN[t-1], only rows the GEMM
// actually wrote (non-first-touch AND a future iteration reads them).
__global__ __launch_bounds__(256) void merge_sth(
    int k, const u16* src, u16* dst)
{
  const int idx = blockIdx.x * 256 + threadIdx.x;   // 0..524287
  const int i = idx >> 5;
  const int s = (idx & 31) * 8;
  const int mask = (1 << k) - 1;
  if ((i & mask) == 0 || (i >> k) == 0) return;
  const int t = ((i >> k) << (k + 1)) | (1 << k) | (i & mask);
  *(short8*)(dst + (size_t)(t - 1) * 256 + s) = *(const short8*)(src + (size_t)(t - 1) * 256 + s);
}

// k=0: odd t are first-touch copies of the leaves. h-half of `out` is final
// only for t=1 (MSB=0); c-half needed for all odd t (read as cl later).
__global__ __launch_bounds__(256) void copy_k0(
    const float* __restrict__ h_bot, const float* __restrict__ c_bot,
    float* __restrict__ out, u16* __restrict__ sth)
{
  const int i = blockIdx.x;          // 0..16383
  const int d = threadIdx.x;
  const int t = 2 * i + 1;
  const float h = h_bot[(size_t)(t - 1) * 256 + d];
  const float c = c_bot[(size_t)(t - 1) * 256 + d];
  if (i == 0) out[(size_t)(t - 1) * 512 + d] = h;
  out[(size_t)(t - 1) * 512 + 256 + d] = c;
  sth[(size_t)(t - 1) * 256 + d] = f2bf(h);
}

// Seed all even t (first touch at k = ctz(t)): state = level-k node.
// Runs once after phase 1. Writes out c-half always; out h-half for pow2 t
// (k == MSB, final — includes t=32768, absorbing old copy_k15); sth for
// non-pow2 t (a future iteration reads it).
__global__ __launch_bounds__(256) void seed_even(
    const u16* __restrict__ hlv, const float* __restrict__ clv,
    float* __restrict__ out, u16* __restrict__ sth)
{
  const int j = blockIdx.x;            // 0..16383
  const int t = 2 * j + 2;
  const int d = threadIdx.x;
  const int k = __ffs(t) - 1;          // >= 1
  const int lk = 32768 - (1 << (16 - k));
  const int nidx = (t >> (k + 1)) * 2;
  const u16 hb  = hlv[(size_t)(lk + nidx) * 256 + d];
  const float c = clv[(size_t)(lk + nidx) * 256 + d];
  out[(size_t)(t - 1) * 512 + 256 + d] = c;
  if ((t & (t - 1)) == 0) {
    out[(size_t)(t - 1) * 512 + d] = bf2f(hb);
  } else {
    sth[(size_t)(t - 1) * 256 + d] = hb;
  }
}

// W (512x1280 fp32) -> gate-permuted W^T (1280x512 bf16).
__global__ __launch_bounds__(256) void transpose_w(
    const float* __restrict__ W, u16* __restrict__ WT)
{
  const int n = blockIdx.x;          // 0..1279 (permuted)
  const int b = n / 160, r = n % 160;
  const int g = r / 32,  dl = r % 32;
  const int col = g * 256 + b * 32 + dl;
  const int tid = threadIdx.x;       // 0..255
  WT[(size_t)n * 512 + tid]       = f2bf(W[(size_t)tid * 1280 + col]);
  WT[(size_t)n * 512 + tid + 256] = f2bf(W[(size_t)(tid + 256) * 1280 + col]);
}

__global__ __launch_bounds__(256) void cast_h0(
    const float* __restrict__ h, u16* __restrict__ h0b)
{
  const size_t i = (size_t)blockIdx.x * 256 + threadIdx.x;
  h0b[i] = f2bf(h[i]);
}

extern "C" void kernel_launch(void* const* d_in, const int* in_sizes, int n_in,
                              void* d_out, int out_size, void* d_ws, size_t ws_size,
                              hipStream_t stream) {
  const float* h_bot = (const float*)d_in[0];
  const float* c_bot = (const float*)d_in[1];
  const float* Wm    = (const float*)d_in[2];
  const float* bmv   = (const float*)d_in[3];
  const float* Wsu   = (const float*)d_in[4];
  const float* bsv   = (const float*)d_in[5];
  float* out = (float*)d_out;
  char* ws = (char*)d_ws;

  u16*   WmT  = (u16*)(ws + 0);
  u16*   WsT  = (u16*)(ws + 1310720);
  u16*   h0b  = (u16*)(ws + 2621440);
  u16*   hlv  = (u16*)(ws + 19398656);
  float* clv  = (float*)(ws + 36175872);
  u16*   sth  = (u16*)(ws + 69730304);
  u16*   sthN = (u16*)(ws + 86507520);

  transpose_w<<<1280, 256, 0, stream>>>(Wm, WmT);
  transpose_w<<<1280, 256, 0, stream>>>(Wsu, WsT);
  cast_h0<<<32768, 256, 0, stream>>>(h_bot, h0b);

  // ---- phase 1: build tree levels (fused; race-free, disjoint levels) ----
  for (int kl = 1; kl <= 15; ++kl) {
    const int M = 32768 >> kl;
    const float* cpar = (kl == 1) ? c_bot : (clv + (size_t)(32768 - (1 << (17 - kl))) * 256);
    float* cout = clv + (size_t)(32768 - (1 << (16 - kl))) * 256;
    u16*   hout = hlv + (size_t)(32768 - (1 << (16 - kl))) * 256;
    const int nbm = (M + 127) / 128;
    gemm_cell<<<nbm * 8, 256, 0, stream>>>(0, kl, M, WmT, bmv, h0b, hlv, sth,
                                           cpar, cout, hout, clv, out, sthN);
  }

  // ---- phase 2: Fenwick accumulation ----
  copy_k0<<<16384, 256, 0, stream>>>(h_bot, c_bot, out, sth);
  seed_even<<<16384, 256, 0, stream>>>(hlv, clv, out, sth);
  for (int kl = 1; kl <= 14; ++kl) {
    const int M = 16384 - (16384 >> kl);   // non-first-touch rows only
    const int nbm = (M + 127) / 128;
    gemm_cell<<<nbm * 8, 256, 0, stream>>>(1, kl, M, WsT, bsv, h0b, hlv, sth,
                                           nullptr, nullptr, nullptr, clv, out, sthN);
    if (kl <= 13) merge_sth<<<2048, 256, 0, stream>>>(kl, sthN, sth);
  }
}

// Round 6
// 984.215 us; speedup vs baseline: 1.2637x; 1.1719x over previous
//
#include <hip/hip_runtime.h>
#include <hip/hip_bf16.h>

// Fenwick TreeLSTM, N=32768, D=256 — fused GEMM+cell.
// Round-6: popcount-parity state double-buffer (merge-free, race-free)
//          + BK=64 swizzled staging (exonerated by the r3/r4/r5 bisect).
//
// BUG HISTORY: rounds 2-5 all shared a single-sth buffer and failed with
// IDENTICAL absmax (incl. r5 = byte-identical gemm to the passing r1) —
// the race: a block stages (reads) the FULL 256-col width of its state rows,
// while the 7 sibling bn-blocks write 32-col slices of those SAME rows in
// the same dispatch. Fix here: row t at iteration k has had
// c = popcount(t mod 2^k) touches (seed + gemm writes at lower set bits);
// touch #n lives in buf[n&1]. Seeds write sthB (touch 1); gemm reads
// buf[c&1] and writes buf[(c+1)&1] — read-buffer != write-buffer for every
// row, always, so full-width reads never collide with slice writes.
//
// Staging (from r2, exonerated): BK=64, each global_load_lds gathers
// 8 rows x 128B (half the L2 requests of r1's 16 x 64B at equal instruction
// count); LDS XOR-swizzle seg^=(row&7) applied on BOTH sides (pre-swizzled
// global source, swizzled ds_read). s_setprio around MFMA; XCD swizzle.

typedef unsigned short u16;
typedef unsigned int u32;
using short8  = __attribute__((ext_vector_type(8))) short;
using float4v = __attribute__((ext_vector_type(4))) float;

// ---- workspace layout (bytes) ----
// WmT  @ 0         : 1280x512 bf16 gate-permuted (1,310,720)
// WsT  @ 1310720   : 1280x512 bf16 gate-permuted (1,310,720)
// h0b  @ 2621440   : 32768x256 bf16 (16,777,216)
// hlv  @ 19398656  : levels 1..15 h bf16 (16,777,216)
// clv  @ 36175872  : levels 1..15 c fp32 (33,554,432)
// sthA @ 69730304  : state_h bf16, parity-0 buffer (16,777,216)
// sthB @ 86507520  : state_h bf16, parity-1 buffer (seeded) (16,777,216)
// total ~103.3 MB (round-0 footprint, known fine)

__device__ __forceinline__ u16 f2bf(float f) {
  u32 u = __float_as_uint(f);
  u = (u + 0x7FFFu + ((u >> 16) & 1u)) >> 16;
  return (u16)u;
}
__device__ __forceinline__ float bf2f(u16 h) {
  return __uint_as_float(((u32)h) << 16);
}
__device__ __forceinline__ float sigf(float x) { return 1.0f / (1.0f + __expf(-x)); }
__device__ __forceinline__ float tanhfast(float x) {
  return 2.0f / (1.0f + __expf(-2.0f * x)) - 1.0f;
}

__device__ __forceinline__ void async16(const void* g, void* l) {
  __builtin_amdgcn_global_load_lds((const __attribute__((address_space(1))) void*)g,
                                   (__attribute__((address_space(3))) void*)l,
                                   16, 0, 0);
}

// A-row gather: row i of A = concat(hl(256 bf16), hr(256 bf16)).
// mode 1 takes PACKED row r (non-first-touch only): i = r + r/(2^k-1) + 1.
// State h for row t read from parity buffer buf[c&1], c = popcount(i & Dk).
__device__ __forceinline__ void row_srcs(int mode, int k, int row,
                                         const u16* h0b, const u16* hlv,
                                         const u16* sthA, const u16* sthB,
                                         const u16*& pL, const u16*& pR) {
  if (mode == 0) {
    const u16* pb = (k == 1) ? h0b : (hlv + (size_t)(32768 - (1 << (17 - k))) * 256);
    pL = pb + (size_t)(2 * row) * 256;
    pR = pb + (size_t)(2 * row + 1) * 256;
  } else {
    const int Dk = (1 << k) - 1;
    const int i = row + row / Dk + 1;
    const int t = ((i >> k) << (k + 1)) | (1 << k) | (i & Dk);
    const int c = __popc(i & Dk);            // touches so far (seed + gemms)
    const u16* sb = (c & 1) ? sthB : sthA;   // touch #c lives in buf[c&1]
    pL = sb + (size_t)(t - 1) * 256;
    const int idx = (t >> (k + 1)) * 2;
    pR = hlv + (size_t)((32768 - (1 << (16 - k))) + idx) * 256;
  }
}

// Fused GEMM + LSTM cell.
// Block tile: 128 rows x 160 cols (5 gates x 32 d), BK=64, 8 K-steps.
// 4 waves as 2(m) x 2(n): wave = 64 rows x 16 d's, acc[4 m-tiles][5 gates].
// LDS: A [2][128][64] u16 @0, B [2][160][64] u16 @16384 -> 73,728 B total.
// Staging: 8 rows x 128B per inst (8 lanes/row x 16B); seg XOR row&7 swizzle.
__global__ __launch_bounds__(256) void gemm_cell(
    int mode, int k, int Mc,
    const u16* WT, const float* bias,
    const u16* h0b, const u16* hlv, u16* sthA, u16* sthB,
    const float* cpar, float* cout, u16* hout,
    const float* clv, float* out)
{
  __shared__ __align__(16) u16 smem[36864];
  const int tid  = threadIdx.x;
  const int lane = tid & 63;
  const int w    = tid >> 6;
  const int wm   = w >> 1, wn = w & 1;

  // XCD swizzle (bijective: grid is always a multiple of 8)
  const int nwg = gridDim.x;
  const int q8  = nwg >> 3;
  const int id  = (blockIdx.x & 7) * q8 + (blockIdx.x >> 3);
  const int bm  = id >> 3, bn = id & 7;

  // ---- staging geometry: inst covers 8 rows; lane = rr*8 + seg (16B segs)
  const int rr  = lane >> 3;        // row within 8-row group
  const int seg = lane & 7;         // 16B segment within 128B row-chunk
  const int swz = ((seg ^ rr) - seg) * 8;  // u16 delta: seg -> seg ^ (row&7)
  // (row&7) == rr for all our groups since group bases are multiples of 8.

  // A: 4 insts/wave; thread's row for inst j: rj = (w*4+j)*8 + rr
  const u16 *aL[4], *aR[4];
#pragma unroll
  for (int j = 0; j < 4; ++j) {
    int rl = bm * 128 + (w * 4 + j) * 8 + rr;
    if (rl > Mc - 1) rl = Mc - 1;
    const u16 *pL, *pR;
    row_srcs(mode, k, rl, h0b, hlv, sthA, sthB, pL, pR);
    aL[j] = pL + seg * 8 + swz;     // = pL + (seg^rr)*8
    aR[j] = pR + seg * 8 + swz;
  }
  // B: 5 insts/wave; thread's WT row for inst j: nj = (w*5+j)*8 + rr
  const u16* pB[5];
#pragma unroll
  for (int j = 0; j < 5; ++j)
    pB[j] = WT + (size_t)(bn * 160 + (w * 5 + j) * 8 + rr) * 512 + seg * 8 + swz;

  float4v acc[4][5];
#pragma unroll
  for (int i = 0; i < 4; ++i)
#pragma unroll
    for (int j = 0; j < 5; ++j) acc[i][j] = (float4v){0.f, 0.f, 0.f, 0.f};

  const int mrow = lane & 15;
  const int kg   = lane >> 4;
  const int m7   = mrow & 7;

  // stage K64-chunk kk2 (0..7) into buffer buf (0/1). 9 insts/wave, each
  // 8 rows x 128B = 8 x 128B L2 requests. LDS dest is linear (lane*16).
#define STAGE(buf, kk2)                                                        \
  {                                                                            \
    const int offA = (kk2 & 3) * 64;                                           \
    _Pragma("unroll")                                                          \
    for (int j = 0; j < 4; ++j)                                                \
      async16(((kk2) < 4 ? aL[j] : aR[j]) + offA,                              \
              smem + (buf) * 8192 + (w * 4 + j) * 512);                        \
    _Pragma("unroll")                                                          \
    for (int j = 0; j < 5; ++j)                                                \
      async16(pB[j] + (kk2) * 64,                                              \
              smem + 16384 + (buf) * 10240 + (w * 5 + j) * 512);               \
  }

  STAGE(0, 0);
  __syncthreads();   // full vmcnt+lgkmcnt drain + barrier (compiler-ordered)

#pragma unroll
  for (int s = 0; s < 8; ++s) {
    const int cur = s & 1;
    if (s < 7) STAGE(cur ^ 1, s + 1);
    const u16* aT = smem + cur * 8192;            // [128][64] swizzled
    const u16* bT = smem + 16384 + cur * 10240;   // [160][64] swizzled
#pragma unroll
    for (int kkk = 0; kkk < 2; ++kkk) {
      short8 af[4], bfv[5];
      const int js = ((kkk * 4 + kg) ^ m7) * 8;   // swizzled 16B slot
#pragma unroll
      for (int mt = 0; mt < 4; ++mt)
        af[mt] = *(const short8*)(aT + (wm * 64 + mt * 16 + mrow) * 64 + js);
#pragma unroll
      for (int g = 0; g < 5; ++g)
        bfv[g] = *(const short8*)(bT + (g * 32 + wn * 16 + mrow) * 64 + js);
      __builtin_amdgcn_s_setprio(1);
#pragma unroll
      for (int mt = 0; mt < 4; ++mt)
#pragma unroll
        for (int g = 0; g < 5; ++g)
          acc[mt][g] = __builtin_amdgcn_mfma_f32_16x16x32_bf16(af[mt], bfv[g], acc[mt][g], 0, 0, 0);
      __builtin_amdgcn_s_setprio(0);
    }
    __syncthreads();  // drains STAGE's vmcnt AND this iter's lgkmcnt
  }
#undef STAGE

  // ---- fused cell epilogue ----
  // lane owns d = bn*32 + wn*16 + mrow; rows r0..r0+3 per m-tile.
  const int d = bn * 32 + wn * 16 + mrow;
  const float bi  = bias[d];
  const float bo_ = bias[256 + d];
  const float bu  = bias[512 + d];
  const float bfl = bias[768 + d];
  const float bfr2= bias[1024 + d];

#pragma unroll
  for (int mt = 0; mt < 4; ++mt) {
    const int r0 = bm * 128 + wm * 64 + mt * 16 + kg * 4;
#pragma unroll
    for (int r = 0; r < 4; ++r) {
      const int row = r0 + r;
      if (row >= Mc) continue;
      const float zi  = acc[mt][0][r] + bi;
      const float zo  = acc[mt][1][r] + bo_;
      const float zu  = acc[mt][2][r] + bu;
      const float zfl = acc[mt][3][r] + bfl;
      const float zfr = acc[mt][4][r] + bfr2;
      if (mode == 0) {
        const float cl = cpar[(size_t)(2 * row) * 256 + d];
        const float cr = cpar[(size_t)(2 * row + 1) * 256 + d];
        const float c = sigf(zi) * tanhfast(zu) + sigf(zfl) * cl + sigf(zfr) * cr;
        const float h = sigf(zo) * tanhfast(c);
        cout[(size_t)row * 256 + d] = c;
        hout[(size_t)row * 256 + d] = f2bf(h);
      } else {
        // packed row -> logical i; all rows are non-first-touch here
        const int Dk  = (1 << k) - 1;
        const int i   = row + row / Dk + 1;
        const int t   = ((i >> k) << (k + 1)) | (1 << k) | (i & Dk);
        const int lk  = 32768 - (1 << (16 - k));
        const int idx = (t >> (k + 1)) * 2;
        const float cr = clv[(size_t)(lk + idx) * 256 + d];
        const float cl = out[(size_t)(t - 1) * 512 + 256 + d];
        const float c = sigf(zi) * tanhfast(zu) + sigf(zfl) * cl + sigf(zfr) * cr;
        const float h = sigf(zo) * tanhfast(c);
        out[(size_t)(t - 1) * 512 + 256 + d] = c;
        if ((i >> k) == 0) {
          out[(size_t)(t - 1) * 512 + d] = h;  // k == MSB(t): final h
        } else {
          // touch #(c+1) -> buf[(c+1)&1]; read was buf[c&1] (never same)
          const int cpc = __popc(i & Dk);
          u16* dst = (cpc & 1) ? sthA : sthB;
          dst[(size_t)(t - 1) * 256 + d] = f2bf(h);
        }
      }
    }
  }
}

// k=0: odd t are first-touch copies of the leaves. Seed = touch #1 -> sthB.
__global__ __launch_bounds__(256) void copy_k0(
    const float* __restrict__ h_bot, const float* __restrict__ c_bot,
    float* __restrict__ out, u16* __restrict__ sthB)
{
  const int i = blockIdx.x;          // 0..16383
  const int d = threadIdx.x;
  const int t = 2 * i + 1;
  const float h = h_bot[(size_t)(t - 1) * 256 + d];
  const float c = c_bot[(size_t)(t - 1) * 256 + d];
  if (i == 0) out[(size_t)(t - 1) * 512 + d] = h;
  out[(size_t)(t - 1) * 512 + 256 + d] = c;
  sthB[(size_t)(t - 1) * 256 + d] = f2bf(h);
}

// Seed all even t (first touch at k = ctz(t)): state = level-k node.
// Seed = touch #1 -> sthB (non-pow2 t); pow2 t are final -> out h-half.
__global__ __launch_bounds__(256) void seed_even(
    const u16* __restrict__ hlv, const float* __restrict__ clv,
    float* __restrict__ out, u16* __restrict__ sthB)
{
  const int j = blockIdx.x;            // 0..16383
  const int t = 2 * j + 2;
  const int d = threadIdx.x;
  const int k = __ffs(t) - 1;          // >= 1
  const int lk = 32768 - (1 << (16 - k));
  const int nidx = (t >> (k + 1)) * 2;
  const u16 hb  = hlv[(size_t)(lk + nidx) * 256 + d];
  const float c = clv[(size_t)(lk + nidx) * 256 + d];
  out[(size_t)(t - 1) * 512 + 256 + d] = c;
  if ((t & (t - 1)) == 0) {
    out[(size_t)(t - 1) * 512 + d] = bf2f(hb);
  } else {
    sthB[(size_t)(t - 1) * 256 + d] = hb;
  }
}

// W (512x1280 fp32) -> gate-permuted W^T (1280x512 bf16).
__global__ __launch_bounds__(256) void transpose_w(
    const float* __restrict__ W, u16* __restrict__ WT)
{
  const int n = blockIdx.x;          // 0..1279 (permuted)
  const int b = n / 160, r = n % 160;
  const int g = r / 32,  dl = r % 32;
  const int col = g * 256 + b * 32 + dl;
  const int tid = threadIdx.x;       // 0..255
  WT[(size_t)n * 512 + tid]       = f2bf(W[(size_t)tid * 1280 + col]);
  WT[(size_t)n * 512 + tid + 256] = f2bf(W[(size_t)(tid + 256) * 1280 + col]);
}

__global__ __launch_bounds__(256) void cast_h0(
    const float* __restrict__ h, u16* __restrict__ h0b)
{
  const size_t i = (size_t)blockIdx.x * 256 + threadIdx.x;
  h0b[i] = f2bf(h[i]);
}

extern "C" void kernel_launch(void* const* d_in, const int* in_sizes, int n_in,
                              void* d_out, int out_size, void* d_ws, size_t ws_size,
                              hipStream_t stream) {
  const float* h_bot = (const float*)d_in[0];
  const float* c_bot = (const float*)d_in[1];
  const float* Wm    = (const float*)d_in[2];
  const float* bmv   = (const float*)d_in[3];
  const float* Wsu   = (const float*)d_in[4];
  const float* bsv   = (const float*)d_in[5];
  float* out = (float*)d_out;
  char* ws = (char*)d_ws;

  u16*   WmT  = (u16*)(ws + 0);
  u16*   WsT  = (u16*)(ws + 1310720);
  u16*   h0b  = (u16*)(ws + 2621440);
  u16*   hlv  = (u16*)(ws + 19398656);
  float* clv  = (float*)(ws + 36175872);
  u16*   sthA = (u16*)(ws + 69730304);
  u16*   sthB = (u16*)(ws + 86507520);

  transpose_w<<<1280, 256, 0, stream>>>(Wm, WmT);
  transpose_w<<<1280, 256, 0, stream>>>(Wsu, WsT);
  cast_h0<<<32768, 256, 0, stream>>>(h_bot, h0b);

  // ---- phase 1: build tree levels (fused; race-free, disjoint levels) ----
  for (int kl = 1; kl <= 15; ++kl) {
    const int M = 32768 >> kl;
    const float* cpar = (kl == 1) ? c_bot : (clv + (size_t)(32768 - (1 << (17 - kl))) * 256);
    float* cout = clv + (size_t)(32768 - (1 << (16 - kl))) * 256;
    u16*   hout = hlv + (size_t)(32768 - (1 << (16 - kl))) * 256;
    const int nbm = (M + 127) / 128;
    gemm_cell<<<nbm * 8, 256, 0, stream>>>(0, kl, M, WmT, bmv, h0b, hlv,
                                           sthA, sthB,
                                           cpar, cout, hout, clv, out);
  }

  // ---- phase 2: Fenwick accumulation (parity buffers, no merges) ----
  copy_k0<<<16384, 256, 0, stream>>>(h_bot, c_bot, out, sthB);
  seed_even<<<16384, 256, 0, stream>>>(hlv, clv, out, sthB);
  for (int kl = 1; kl <= 14; ++kl) {
    const int M = 16384 - (16384 >> kl);   // non-first-touch rows only
    const int nbm = (M + 127) / 128;
    gemm_cell<<<nbm * 8, 256, 0, stream>>>(1, kl, M, WsT, bsv, h0b, hlv,
                                           sthA, sthB,
                                           nullptr, nullptr, nullptr, clv, out);
  }
}